// Round 8
// baseline (847.698 us; speedup 1.0000x reference)
//
#include <hip/hip_runtime.h>
#include <math.h>

#define N_NODES 100000
#define N_EDGES 1600000
#define IN_C 512
#define HID_C 128
#define OUT_C 64
#define N_LAYERS 8

typedef short bf16x8 __attribute__((ext_vector_type(8)));
typedef float f32x4 __attribute__((ext_vector_type(4)));

static __device__ __forceinline__ ushort f2bf(float f) {
  uint u = __float_as_uint(f);
  u = (u + 0x7FFFu + ((u >> 16) & 1u)) >> 16;
  return (ushort)u;
}
static __device__ __forceinline__ float bflo(uint u) { return __uint_as_float(u << 16); }
static __device__ __forceinline__ float bfhi(uint u) { return __uint_as_float(u & 0xffff0000u); }

// ---------------------------------------------------------------------------
// CSR build: hist -> scan -> bin-sort (pass A: bin by dst>>10 with coalesced
// run writes; pass B: per-bin LDS cursors, writes confined to 64KB window)
// ---------------------------------------------------------------------------
__global__ __launch_bounds__(256) void hist_kernel(const int* __restrict__ dst,
                                                   int* __restrict__ cnt) {
  int e = blockIdx.x * 256 + threadIdx.x;
  atomicAdd(&cnt[dst[e]], 1);
}

__global__ __launch_bounds__(256) void scan_block(const int* __restrict__ in,
                                                  int* __restrict__ out,
                                                  int* __restrict__ bsum, int n) {
  __shared__ int tsum[256];
  int t = threadIdx.x;
  int base = blockIdx.x * 1024 + t * 4;
  int v0 = (base + 0 < n) ? in[base + 0] : 0;
  int v1 = (base + 1 < n) ? in[base + 1] : 0;
  int v2 = (base + 2 < n) ? in[base + 2] : 0;
  int v3 = (base + 3 < n) ? in[base + 3] : 0;
  int s = v0 + v1 + v2 + v3;
  tsum[t] = s;
  __syncthreads();
  for (int off = 1; off < 256; off <<= 1) {
    int x = (t >= off) ? tsum[t - off] : 0;
    __syncthreads();
    tsum[t] += x;
    __syncthreads();
  }
  int excl = tsum[t] - s;
  int i0 = excl + v0, i1 = i0 + v1, i2 = i1 + v2, i3 = i2 + v3;
  if (base + 0 < n) out[base + 0] = i0;
  if (base + 1 < n) out[base + 1] = i1;
  if (base + 2 < n) out[base + 2] = i2;
  if (base + 3 < n) out[base + 3] = i3;
  if (t == 255 && bsum) bsum[blockIdx.x] = tsum[255];
}

__global__ __launch_bounds__(256) void finalize_rows(const int* __restrict__ incl,
                                                     const int* __restrict__ auxi,
                                                     int* __restrict__ row, int n) {
  int i = blockIdx.x * 256 + threadIdx.x;
  if (i < n) {
    int g = i >> 10;
    int off = g ? auxi[g - 1] : 0;
    row[i + 1] = incl[i] + off;
    if (i == 0) row[0] = 0;
  }
}

__global__ __launch_bounds__(128) void init_bincur(const int* __restrict__ row,
                                                   int* __restrict__ bincur) {
  int b = threadIdx.x;  // 128 bins
  int n0 = b << 10;
  bincur[b] = row[n0 < N_NODES ? n0 : N_NODES];
}

// Pass A: bin edges by dst>>10. Block stages 2048 edges, LDS counting sort,
// bulk cursor alloc (1 atomic per bin per block), coalesced run writes.
// bb entry: x = payload (w15<<17 | src17), y = full dst (bin = y>>10).
__global__ __launch_bounds__(256) void bin_scatter(const int* __restrict__ src,
                                                   const int* __restrict__ dst,
                                                   const float* __restrict__ w,
                                                   int* __restrict__ bincur,
                                                   uint2* __restrict__ bb) {
  __shared__ uint2 ebuf[2048];
  __shared__ int hist[128];
  __shared__ int lstart[128];
  __shared__ int gbase[128];
  int tid = threadIdx.x;
  int base = blockIdx.x * 2048;
  int cnt = N_EDGES - base;
  if (cnt > 2048) cnt = 2048;
  if (tid < 128) hist[tid] = 0;
  __syncthreads();
  uint pay[8];
  int bn[8], rk[8], dfull[8];
#pragma unroll
  for (int i = 0; i < 8; i++) {
    int idx = tid + i * 256;
    if (idx < cnt) {
      int e = base + idx;
      int d = dst[e];
      uint fb = __float_as_uint(w[e]) + 0x8000u;
      pay[i] = ((fb >> 16) << 17) | (uint)src[e];
      dfull[i] = d;
      bn[i] = d >> 10;
      rk[i] = atomicAdd(&hist[bn[i]], 1);
    }
  }
  __syncthreads();
  if (tid == 0) {
    int acc = 0;
    for (int b = 0; b < 128; b++) { lstart[b] = acc; acc += hist[b]; }
  }
  __syncthreads();
  if (tid < 128 && hist[tid] > 0) gbase[tid] = atomicAdd(&bincur[tid], hist[tid]);
  __syncthreads();
#pragma unroll
  for (int i = 0; i < 8; i++) {
    int idx = tid + i * 256;
    if (idx < cnt) ebuf[lstart[bn[i]] + rk[i]] = make_uint2(pay[i], (uint)dfull[i]);
  }
  __syncthreads();
#pragma unroll
  for (int i = 0; i < 8; i++) {
    int j = tid + i * 256;
    if (j < cnt) {
      uint2 v = ebuf[j];
      int b = (int)(v.y >> 10);
      bb[gbase[b] + (j - lstart[b])] = v;
    }
  }
}

// Pass B: one block per bin (1024 nodes). LDS per-node cursors seeded from ROW;
// final epk writes land in this bin's contiguous ~64KB CSR window only.
__global__ __launch_bounds__(256) void bin_place(const uint2* __restrict__ bb,
                                                 const int* __restrict__ row,
                                                 uint* __restrict__ epk) {
  __shared__ int lcur[1024];
  int b = blockIdx.x;
  int n0 = b << 10;
  int tid = threadIdx.x;
  for (int i = tid; i < 1024; i += 256) {
    int d = n0 + i;
    lcur[i] = (d < N_NODES) ? row[d] : 0;
  }
  __syncthreads();
  int hi = n0 + 1024;
  if (hi > N_NODES) hi = N_NODES;
  int beg = row[n0], end = row[hi];
  for (int j = beg + tid; j < end; j += 256) {
    uint2 v = bb[j];
    int p = atomicAdd(&lcur[v.y & 1023u], 1);
    epk[p] = v.x;
  }
}

// ---------------------------------------------------------------------------
// Pre-cast weights fp32 -> bf16 (W_convs transposed per layer)
// ---------------------------------------------------------------------------
__global__ __launch_bounds__(256) void cast_weights(const float* __restrict__ we,
                                                    const float* __restrict__ wc,
                                                    const float* __restrict__ wd,
                                                    ushort* __restrict__ web,
                                                    ushort* __restrict__ wcb,
                                                    ushort* __restrict__ wdb) {
  int i = blockIdx.x * 256 + threadIdx.x;
  if (i < 128 * 512) web[i] = f2bf(we[i]);
  if (i < 8 * 128 * 128) {
    int layer = i >> 14, rem = i & 16383, k = rem >> 7, j = rem & 127;
    wcb[(layer << 14) + (j << 7) + k] = f2bf(wc[i]);  // wcb[l][j][k] = W[l][k][j]
  }
  if (i < 64 * 128) wdb[i] = f2bf(wd[i]);
}

// ---------------------------------------------------------------------------
// Encoder MFMA: h = x @ W_enc.T  x:[N,512]fp32, W:[128,512]bf16 -> h:[N,128]bf16
// ---------------------------------------------------------------------------
__global__ __launch_bounds__(256) void enc_mfma(const float* __restrict__ x,
                                                const ushort* __restrict__ wb,
                                                ushort* __restrict__ h) {
  __shared__ ushort xs[32][136];
  __shared__ ushort ws[128][136];
  int tid = threadIdx.x;
  size_t row0 = (size_t)blockIdx.x * 32;
  int lane = tid & 63;
  int wv = tid >> 6;
  int m0 = (wv >> 1) * 16;
  int n0 = (wv & 1) * 64;
  int arow = m0 + (lane & 15);
  int akb = (lane >> 4) * 8;
  f32x4 acc[4] = {};
  for (int kc = 0; kc < 4; kc++) {
    int k0 = kc * 128;
    __syncthreads();
#pragma unroll
    for (int i = 0; i < 4; i++) {
      int u = tid + i * 256;
      int r = u >> 5, c4 = u & 31;
      float4 v = *(const float4*)(x + (row0 + r) * IN_C + k0 + c4 * 4);
      uint2 p;
      p.x = (uint)f2bf(v.x) | ((uint)f2bf(v.y) << 16);
      p.y = (uint)f2bf(v.z) | ((uint)f2bf(v.w) << 16);
      *(uint2*)&xs[r][c4 * 4] = p;
    }
#pragma unroll
    for (int i = 0; i < 8; i++) {
      int u = tid + i * 256;
      int c = u >> 4, o = u & 15;
      *(uint4*)&ws[c][o * 8] = *(const uint4*)(wb + (size_t)c * IN_C + k0 + o * 8);
    }
    __syncthreads();
#pragma unroll
    for (int ks = 0; ks < 4; ks++) {
      int kk = ks * 32 + akb;
      bf16x8 a = *(bf16x8*)&xs[arow][kk];
#pragma unroll
      for (int n = 0; n < 4; n++) {
        bf16x8 b = *(bf16x8*)&ws[n0 + n * 16 + (lane & 15)][kk];
        acc[n] = __builtin_amdgcn_mfma_f32_16x16x32_bf16(a, b, acc[n], 0, 0, 0);
      }
    }
  }
  int crow = m0 + (lane >> 4) * 4;
  int ccol = lane & 15;
#pragma unroll
  for (int n = 0; n < 4; n++)
#pragma unroll
    for (int r = 0; r < 4; r++)
      h[(row0 + crow + r) * HID_C + n0 + n * 16 + ccol] = f2bf(acc[n][r]);
}

// ---------------------------------------------------------------------------
// Aggregation: hh[n] = 0.9*sum w_e*h[src_e] + 0.1*x0[n]
// One wave per node, lane = 2 channels, masked 8-deep batches (MLP=8).
// ---------------------------------------------------------------------------
__global__ __launch_bounds__(256) void agg_bf(const ushort* __restrict__ h,
                                              const ushort* __restrict__ x0,
                                              const int* __restrict__ row,
                                              const uint* __restrict__ epk,
                                              ushort* __restrict__ out) {
  int node = (blockIdx.x * 256 + threadIdx.x) >> 6;
  int lane = threadIdx.x & 63;
  int beg = row[node], end = row[node + 1];
  float a0 = 0.f, a1 = 0.f;
  const uint* hp = (const uint*)h + lane;  // h row = 64 uints
  for (int e = beg; e < end; e += 8) {
    uint p0 = (e + 0 < end) ? epk[e + 0] : 0u;
    uint p1 = (e + 1 < end) ? epk[e + 1] : 0u;
    uint p2 = (e + 2 < end) ? epk[e + 2] : 0u;
    uint p3 = (e + 3 < end) ? epk[e + 3] : 0u;
    uint p4 = (e + 4 < end) ? epk[e + 4] : 0u;
    uint p5 = (e + 5 < end) ? epk[e + 5] : 0u;
    uint p6 = (e + 6 < end) ? epk[e + 6] : 0u;
    uint p7 = (e + 7 < end) ? epk[e + 7] : 0u;
    uint h0 = hp[(size_t)(p0 & 0x1FFFFu) * 64];
    uint h1 = hp[(size_t)(p1 & 0x1FFFFu) * 64];
    uint h2 = hp[(size_t)(p2 & 0x1FFFFu) * 64];
    uint h3 = hp[(size_t)(p3 & 0x1FFFFu) * 64];
    uint h4 = hp[(size_t)(p4 & 0x1FFFFu) * 64];
    uint h5 = hp[(size_t)(p5 & 0x1FFFFu) * 64];
    uint h6 = hp[(size_t)(p6 & 0x1FFFFu) * 64];
    uint h7 = hp[(size_t)(p7 & 0x1FFFFu) * 64];
    float w0 = __uint_as_float((p0 >> 17) << 16);
    float w1 = __uint_as_float((p1 >> 17) << 16);
    float w2 = __uint_as_float((p2 >> 17) << 16);
    float w3 = __uint_as_float((p3 >> 17) << 16);
    float w4 = __uint_as_float((p4 >> 17) << 16);
    float w5 = __uint_as_float((p5 >> 17) << 16);
    float w6 = __uint_as_float((p6 >> 17) << 16);
    float w7 = __uint_as_float((p7 >> 17) << 16);
    a0 = fmaf(w0, bflo(h0), a0); a1 = fmaf(w0, bfhi(h0), a1);
    a0 = fmaf(w1, bflo(h1), a0); a1 = fmaf(w1, bfhi(h1), a1);
    a0 = fmaf(w2, bflo(h2), a0); a1 = fmaf(w2, bfhi(h2), a1);
    a0 = fmaf(w3, bflo(h3), a0); a1 = fmaf(w3, bfhi(h3), a1);
    a0 = fmaf(w4, bflo(h4), a0); a1 = fmaf(w4, bfhi(h4), a1);
    a0 = fmaf(w5, bflo(h5), a0); a1 = fmaf(w5, bfhi(h5), a1);
    a0 = fmaf(w6, bflo(h6), a0); a1 = fmaf(w6, bfhi(h6), a1);
    a0 = fmaf(w7, bflo(h7), a0); a1 = fmaf(w7, bfhi(h7), a1);
  }
  uint xv = ((const uint*)x0)[(size_t)node * 64 + lane];
  float o0 = 0.9f * a0 + 0.1f * bflo(xv);
  float o1 = 0.9f * a1 + 0.1f * bfhi(xv);
  ((uint*)out)[(size_t)node * 64 + lane] = (uint)f2bf(o0) | ((uint)f2bf(o1) << 16);
}

// ---------------------------------------------------------------------------
// Conv MFMA (in-place), 64 rows/block: h = relu((1-b)*hh + b*(hh @ W))
// wb is W^T per layer. Wave wv owns rows [wv*16, wv*16+16), full 128 cols.
// ---------------------------------------------------------------------------
__global__ __launch_bounds__(256) void conv_mfma(ushort* __restrict__ hbuf,
                                                 const ushort* __restrict__ wb,
                                                 float onemb, float beta) {
  __shared__ ushort hs[64][136];
  __shared__ ushort ws[128][136];
  int tid = threadIdx.x;
  size_t row0 = (size_t)blockIdx.x * 64;
#pragma unroll
  for (int i = 0; i < 4; i++) {
    int u = tid + i * 256;
    int r = u >> 4, o = u & 15;
    if (row0 + r < N_NODES)
      *(uint4*)&hs[r][o * 8] = *(const uint4*)(hbuf + (row0 + r) * HID_C + o * 8);
  }
#pragma unroll
  for (int i = 0; i < 8; i++) {
    int u = tid + i * 256;
    int c = u >> 4, o = u & 15;
    *(uint4*)&ws[c][o * 8] = *(const uint4*)(wb + (size_t)c * HID_C + o * 8);
  }
  __syncthreads();
  int lane = tid & 63;
  int wv = tid >> 6;
  int m0 = wv * 16;
  int arow = m0 + (lane & 15), akb = (lane >> 4) * 8;
  f32x4 acc[8] = {};
#pragma unroll
  for (int ks = 0; ks < 4; ks++) {
    int kk = ks * 32 + akb;
    bf16x8 a = *(bf16x8*)&hs[arow][kk];
#pragma unroll
    for (int n = 0; n < 8; n++) {
      bf16x8 b = *(bf16x8*)&ws[n * 16 + (lane & 15)][kk];
      acc[n] = __builtin_amdgcn_mfma_f32_16x16x32_bf16(a, b, acc[n], 0, 0, 0);
    }
  }
  int crow = m0 + (lane >> 4) * 4, ccol = lane & 15;
#pragma unroll
  for (int n = 0; n < 8; n++)
#pragma unroll
    for (int r = 0; r < 4; r++) {
      if (row0 + crow + r < N_NODES) {
        float hv = bflo((uint)hs[crow + r][n * 16 + ccol]);
        float o = fmaxf(onemb * hv + beta * acc[n][r], 0.f);
        hbuf[(row0 + crow + r) * HID_C + n * 16 + ccol] = f2bf(o);
      }
    }
}

// ---------------------------------------------------------------------------
// Decoder MFMA: out = h @ W_dec.T -> fp32 [N,64]
// ---------------------------------------------------------------------------
__global__ __launch_bounds__(256) void dec_mfma(const ushort* __restrict__ h,
                                                const ushort* __restrict__ wb,
                                                float* __restrict__ out) {
  __shared__ ushort hs[32][136];
  __shared__ ushort ws[64][136];
  int tid = threadIdx.x;
  size_t row0 = (size_t)blockIdx.x * 32;
  {
    int r = tid >> 3, o = tid & 7;
    *(uint4*)&hs[r][o * 16] = *(const uint4*)(h + (row0 + r) * HID_C + o * 16);
    *(uint4*)&hs[r][o * 16 + 8] = *(const uint4*)(h + (row0 + r) * HID_C + o * 16 + 8);
  }
#pragma unroll
  for (int i = 0; i < 4; i++) {
    int u = tid + i * 256;
    int c = u >> 4, o = u & 15;
    *(uint4*)&ws[c][o * 8] = *(const uint4*)(wb + (size_t)c * HID_C + o * 8);
  }
  __syncthreads();
  int lane = tid & 63, wv = tid >> 6;
  int m0 = (wv >> 1) * 16, n0 = (wv & 1) * 32;
  int arow = m0 + (lane & 15), akb = (lane >> 4) * 8;
  f32x4 acc[2] = {};
#pragma unroll
  for (int ks = 0; ks < 4; ks++) {
    int kk = ks * 32 + akb;
    bf16x8 a = *(bf16x8*)&hs[arow][kk];
#pragma unroll
    for (int n = 0; n < 2; n++) {
      bf16x8 b = *(bf16x8*)&ws[n0 + n * 16 + (lane & 15)][kk];
      acc[n] = __builtin_amdgcn_mfma_f32_16x16x32_bf16(a, b, acc[n], 0, 0, 0);
    }
  }
  int crow = m0 + (lane >> 4) * 4, ccol = lane & 15;
#pragma unroll
  for (int n = 0; n < 2; n++)
#pragma unroll
    for (int r = 0; r < 4; r++)
      out[(row0 + crow + r) * OUT_C + n0 + n * 16 + ccol] = acc[n][r];
}

// ---------------------------------------------------------------------------
extern "C" void kernel_launch(void* const* d_in, const int* in_sizes, int n_in,
                              void* d_out, int out_size, void* d_ws, size_t ws_size,
                              hipStream_t stream) {
  const float* x = (const float*)d_in[0];
  const int* ei = (const int*)d_in[1];
  const float* ew = (const float*)d_in[2];
  const float* Wenc = (const float*)d_in[3];
  const float* Wconvs = (const float*)d_in[4];
  const float* Wdec = (const float*)d_in[5];
  float* out = (float*)d_out;

  char* p = (char*)d_ws;
  ushort* H0 = (ushort*)p; p += (size_t)N_NODES * HID_C * 2;
  ushort* HA = (ushort*)p; p += (size_t)N_NODES * HID_C * 2;
  ushort* HB = (ushort*)p; p += (size_t)N_NODES * HID_C * 2;
  uint* EPK = (uint*)p;    p += (size_t)N_EDGES * 4;
  uint2* BB = (uint2*)p;   p += (size_t)N_EDGES * 8;
  ushort* WENC = (ushort*)p;  p += 128 * 512 * 2;
  ushort* WCONV = (ushort*)p; p += 8 * 128 * 128 * 2;
  ushort* WDEC = (ushort*)p;  p += 64 * 128 * 2;
  int* ROW = (int*)p;  p += (N_NODES + 1) * 4;
  int* CNT = (int*)p;  p += N_NODES * 4;
  int* INCL = (int*)p; p += N_NODES * 4;
  int* BINCUR = (int*)p; p += 128 * 4;
  int* AUX = (int*)p;  p += 128 * 4;
  int* AUXI = (int*)p;

  const int* src = ei;
  const int* dst = ei + N_EDGES;

  // weights -> bf16 (W_convs transposed per layer)
  cast_weights<<<512, 256, 0, stream>>>(Wenc, Wconvs, Wdec, WENC, WCONV, WDEC);

  // CSR build
  hipMemsetAsync(CNT, 0, N_NODES * sizeof(int), stream);
  hist_kernel<<<N_EDGES / 256, 256, 0, stream>>>(dst, CNT);
  scan_block<<<98, 256, 0, stream>>>(CNT, INCL, AUX, N_NODES);
  scan_block<<<1, 256, 0, stream>>>(AUX, AUXI, nullptr, 98);
  finalize_rows<<<391, 256, 0, stream>>>(INCL, AUXI, ROW, N_NODES);
  init_bincur<<<1, 128, 0, stream>>>(ROW, BINCUR);
  bin_scatter<<<(N_EDGES + 2047) / 2048, 256, 0, stream>>>(src, dst, ew, BINCUR, BB);
  bin_place<<<98, 256, 0, stream>>>(BB, ROW, EPK);

  // encoder
  enc_mfma<<<3125, 256, 0, stream>>>(x, WENC, H0);

  // layers
  const ushort* cur = H0;
  ushort* bufs[2] = {HA, HB};
  for (int i = 0; i < N_LAYERS; i++) {
    ushort* nxt = bufs[i & 1];
    agg_bf<<<25000, 256, 0, stream>>>(cur, H0, ROW, EPK, nxt);
    float beta = logf(0.5f / (float)(i + 1) + 1.0f);
    conv_mfma<<<1563, 256, 0, stream>>>(nxt, WCONV + (size_t)i * HID_C * HID_C,
                                        1.0f - beta, beta);
    cur = nxt;
  }

  // decoder
  dec_mfma<<<3125, 256, 0, stream>>>(cur, WDEC, out);
}

// Round 10
// 820.142 us; speedup vs baseline: 1.0336x; 1.0336x over previous
//
#include <hip/hip_runtime.h>
#include <math.h>

#define N_NODES 100000
#define N_EDGES 1600000
#define IN_C 512
#define HID_C 128
#define OUT_C 64
#define N_LAYERS 8
// edges per 1024-node bin: mean = 1.6M*1024/100000 = 16384, sigma ~127.
// MUST exceed mean by many sigma: 18432 = mean + 16 sigma.
#define BINSTRIDE 18432

typedef short bf16x8 __attribute__((ext_vector_type(8)));
typedef float f32x4 __attribute__((ext_vector_type(4)));

static __device__ __forceinline__ ushort f2bf(float f) {
  uint u = __float_as_uint(f);
  u = (u + 0x7FFFu + ((u >> 16) & 1u)) >> 16;
  return (ushort)u;
}
static __device__ __forceinline__ float bflo(uint u) { return __uint_as_float(u << 16); }
static __device__ __forceinline__ float bfhi(uint u) { return __uint_as_float(u & 0xffff0000u); }

// ---------------------------------------------------------------------------
// CSR build, hist-free:
//   init_bincur -> bin_scatter (fixed-stride bins, coalesced run writes)
//   -> bin_count (LDS per-node counts) -> scan -> rows -> bin_place
// ---------------------------------------------------------------------------
__global__ __launch_bounds__(128) void init_bincur(int* __restrict__ bincur) {
  bincur[threadIdx.x] = threadIdx.x * BINSTRIDE;
}

// bb entry: x = payload (w15<<17 | src17), y = full dst (bin = y>>10).
__global__ __launch_bounds__(256) void bin_scatter(const int* __restrict__ src,
                                                   const int* __restrict__ dst,
                                                   const float* __restrict__ w,
                                                   int* __restrict__ bincur,
                                                   uint2* __restrict__ bb) {
  __shared__ uint2 ebuf[2048];
  __shared__ int hist[128];
  __shared__ int lstart[128];
  __shared__ int gbase[128];
  int tid = threadIdx.x;
  int base = blockIdx.x * 2048;
  int cnt = N_EDGES - base;
  if (cnt > 2048) cnt = 2048;
  if (tid < 128) hist[tid] = 0;
  __syncthreads();
  uint pay[8];
  int bn[8], rk[8], dfull[8];
#pragma unroll
  for (int i = 0; i < 8; i++) {
    int idx = tid + i * 256;
    if (idx < cnt) {
      int e = base + idx;
      int d = dst[e];
      uint fb = __float_as_uint(w[e]) + 0x8000u;
      pay[i] = ((fb >> 16) << 17) | (uint)src[e];
      dfull[i] = d;
      bn[i] = d >> 10;
      rk[i] = atomicAdd(&hist[bn[i]], 1);
    }
  }
  __syncthreads();
  if (tid == 0) {
    int acc = 0;
    for (int b = 0; b < 128; b++) { lstart[b] = acc; acc += hist[b]; }
  }
  __syncthreads();
  if (tid < 128 && hist[tid] > 0) gbase[tid] = atomicAdd(&bincur[tid], hist[tid]);
  __syncthreads();
#pragma unroll
  for (int i = 0; i < 8; i++) {
    int idx = tid + i * 256;
    if (idx < cnt) ebuf[lstart[bn[i]] + rk[i]] = make_uint2(pay[i], (uint)dfull[i]);
  }
  __syncthreads();
#pragma unroll
  for (int i = 0; i < 8; i++) {
    int j = tid + i * 256;
    if (j < cnt) {
      uint2 v = ebuf[j];
      int b = (int)(v.y >> 10);
      bb[gbase[b] + (j - lstart[b])] = v;
    }
  }
}

// per-node counts from binned buffer (LDS atomics only)
__global__ __launch_bounds__(256) void bin_count(const uint2* __restrict__ bb,
                                                 const int* __restrict__ bincur,
                                                 int* __restrict__ cnt) {
  __shared__ int lc[1024];
  int b = blockIdx.x;
  int tid = threadIdx.x;
  for (int i = tid; i < 1024; i += 256) lc[i] = 0;
  __syncthreads();
  int beg = b * BINSTRIDE, end = bincur[b];
  for (int j = beg + tid; j < end; j += 256)
    atomicAdd(&lc[bb[j].y & 1023u], 1);
  __syncthreads();
  int n0 = b << 10;
  for (int i = tid; i < 1024; i += 256)
    if (n0 + i < N_NODES) cnt[n0 + i] = lc[i];
}

__global__ __launch_bounds__(256) void scan_block(const int* __restrict__ in,
                                                  int* __restrict__ out,
                                                  int* __restrict__ bsum, int n) {
  __shared__ int tsum[256];
  int t = threadIdx.x;
  int base = blockIdx.x * 1024 + t * 4;
  int v0 = (base + 0 < n) ? in[base + 0] : 0;
  int v1 = (base + 1 < n) ? in[base + 1] : 0;
  int v2 = (base + 2 < n) ? in[base + 2] : 0;
  int v3 = (base + 3 < n) ? in[base + 3] : 0;
  int s = v0 + v1 + v2 + v3;
  tsum[t] = s;
  __syncthreads();
  for (int off = 1; off < 256; off <<= 1) {
    int x = (t >= off) ? tsum[t - off] : 0;
    __syncthreads();
    tsum[t] += x;
    __syncthreads();
  }
  int excl = tsum[t] - s;
  int i0 = excl + v0, i1 = i0 + v1, i2 = i1 + v2, i3 = i2 + v3;
  if (base + 0 < n) out[base + 0] = i0;
  if (base + 1 < n) out[base + 1] = i1;
  if (base + 2 < n) out[base + 2] = i2;
  if (base + 3 < n) out[base + 3] = i3;
  if (t == 255 && bsum) bsum[blockIdx.x] = tsum[255];
}

__global__ __launch_bounds__(256) void finalize_rows(const int* __restrict__ incl,
                                                     const int* __restrict__ auxi,
                                                     int* __restrict__ row, int n) {
  int i = blockIdx.x * 256 + threadIdx.x;
  if (i < n) {
    int g = i >> 10;
    int off = g ? auxi[g - 1] : 0;
    row[i + 1] = incl[i] + off;
    if (i == 0) row[0] = 0;
  }
}

__global__ __launch_bounds__(256) void bin_place(const uint2* __restrict__ bb,
                                                 const int* __restrict__ bincur,
                                                 const int* __restrict__ row,
                                                 uint* __restrict__ epk) {
  __shared__ int lcur[1024];
  int b = blockIdx.x;
  int n0 = b << 10;
  int tid = threadIdx.x;
  for (int i = tid; i < 1024; i += 256) {
    int d = n0 + i;
    lcur[i] = (d < N_NODES) ? row[d] : 0;
  }
  __syncthreads();
  int beg = b * BINSTRIDE, end = bincur[b];
  for (int j = beg + tid; j < end; j += 256) {
    uint2 v = bb[j];
    int p = atomicAdd(&lcur[v.y & 1023u], 1);
    epk[p] = v.x;
  }
}

// ---------------------------------------------------------------------------
// Pre-cast weights fp32 -> bf16 (W_convs transposed per layer)
// ---------------------------------------------------------------------------
__global__ __launch_bounds__(256) void cast_weights(const float* __restrict__ we,
                                                    const float* __restrict__ wc,
                                                    const float* __restrict__ wd,
                                                    ushort* __restrict__ web,
                                                    ushort* __restrict__ wcb,
                                                    ushort* __restrict__ wdb) {
  int i = blockIdx.x * 256 + threadIdx.x;
  if (i < 128 * 512) web[i] = f2bf(we[i]);
  if (i < 8 * 128 * 128) {
    int layer = i >> 14, rem = i & 16383, k = rem >> 7, j = rem & 127;
    wcb[(layer << 14) + (j << 7) + k] = f2bf(wc[i]);  // wcb[l][j][k] = W[l][k][j]
  }
  if (i < 64 * 128) wdb[i] = f2bf(wd[i]);
}

// ---------------------------------------------------------------------------
// Encoder MFMA, 64 rows/block: h = x @ W_enc.T
// x:[N,512]fp32, W:[128,512]bf16 -> h:[N,128]bf16
// 4 waves in 2x2; wave tile 32 rows x 64 cols.
// ---------------------------------------------------------------------------
__global__ __launch_bounds__(256) void enc_mfma(const float* __restrict__ x,
                                                const ushort* __restrict__ wb,
                                                ushort* __restrict__ h) {
  __shared__ ushort xs[64][136];
  __shared__ ushort ws[128][136];
  int tid = threadIdx.x;
  size_t row0 = (size_t)blockIdx.x * 64;
  int lane = tid & 63;
  int wv = tid >> 6;
  int m0 = (wv >> 1) * 32;
  int n0 = (wv & 1) * 64;
  int arow = m0 + (lane & 15);
  int akb = (lane >> 4) * 8;
  f32x4 acc[2][4] = {};
  for (int kc = 0; kc < 4; kc++) {
    int k0 = kc * 128;
    __syncthreads();
#pragma unroll
    for (int i = 0; i < 8; i++) {
      int u = tid + i * 256;
      int r = u >> 5, c4 = u & 31;
      uint2 p = make_uint2(0u, 0u);
      if (row0 + r < N_NODES) {
        float4 v = *(const float4*)(x + (row0 + r) * IN_C + k0 + c4 * 4);
        p.x = (uint)f2bf(v.x) | ((uint)f2bf(v.y) << 16);
        p.y = (uint)f2bf(v.z) | ((uint)f2bf(v.w) << 16);
      }
      *(uint2*)&xs[r][c4 * 4] = p;
    }
#pragma unroll
    for (int i = 0; i < 8; i++) {
      int u = tid + i * 256;
      int c = u >> 4, o = u & 15;
      *(uint4*)&ws[c][o * 8] = *(const uint4*)(wb + (size_t)c * IN_C + k0 + o * 8);
    }
    __syncthreads();
#pragma unroll
    for (int ks = 0; ks < 4; ks++) {
      int kk = ks * 32 + akb;
      bf16x8 a0 = *(bf16x8*)&xs[arow][kk];
      bf16x8 a1 = *(bf16x8*)&xs[arow + 16][kk];
#pragma unroll
      for (int n = 0; n < 4; n++) {
        bf16x8 b = *(bf16x8*)&ws[n0 + n * 16 + (lane & 15)][kk];
        acc[0][n] = __builtin_amdgcn_mfma_f32_16x16x32_bf16(a0, b, acc[0][n], 0, 0, 0);
        acc[1][n] = __builtin_amdgcn_mfma_f32_16x16x32_bf16(a1, b, acc[1][n], 0, 0, 0);
      }
    }
  }
  int crow = m0 + (lane >> 4) * 4;
  int ccol = lane & 15;
#pragma unroll
  for (int m = 0; m < 2; m++)
#pragma unroll
    for (int n = 0; n < 4; n++)
#pragma unroll
      for (int r = 0; r < 4; r++) {
        size_t rr = row0 + crow + m * 16 + r;
        if (rr < N_NODES)
          h[rr * HID_C + n0 + n * 16 + ccol] = f2bf(acc[m][n][r]);
      }
}

// ---------------------------------------------------------------------------
// Aggregation: hh[n] = 0.9*sum w_e*h[src_e] + 0.1*x0[n]
// One wave per node, lane = 2 channels, masked 16-deep batches (MLP=16).
// ---------------------------------------------------------------------------
__global__ __launch_bounds__(256) void agg_bf(const ushort* __restrict__ h,
                                              const ushort* __restrict__ x0,
                                              const int* __restrict__ row,
                                              const uint* __restrict__ epk,
                                              ushort* __restrict__ out) {
  int node = (blockIdx.x * 256 + threadIdx.x) >> 6;
  int lane = threadIdx.x & 63;
  int beg = row[node], end = row[node + 1];
  float a0 = 0.f, a1 = 0.f;
  const uint* hp = (const uint*)h + lane;  // h row = 64 uints
  for (int e = beg; e < end; e += 16) {
    uint pv[16];
    uint hv[16];
#pragma unroll
    for (int k = 0; k < 16; k++) pv[k] = (e + k < end) ? epk[e + k] : 0u;
#pragma unroll
    for (int k = 0; k < 16; k++) hv[k] = hp[(size_t)(pv[k] & 0x1FFFFu) * 64];
#pragma unroll
    for (int k = 0; k < 16; k++) {
      float w = __uint_as_float((pv[k] >> 17) << 16);
      a0 = fmaf(w, bflo(hv[k]), a0);
      a1 = fmaf(w, bfhi(hv[k]), a1);
    }
  }
  uint xv = ((const uint*)x0)[(size_t)node * 64 + lane];
  float o0 = 0.9f * a0 + 0.1f * bflo(xv);
  float o1 = 0.9f * a1 + 0.1f * bfhi(xv);
  ((uint*)out)[(size_t)node * 64 + lane] = (uint)f2bf(o0) | ((uint)f2bf(o1) << 16);
}

// ---------------------------------------------------------------------------
// Conv MFMA (in-place), 64 rows/block: h = relu((1-b)*hh + b*(hh @ W))
// wb is W^T per layer. Wave wv owns rows [wv*16, +16), full 128 cols.
// ---------------------------------------------------------------------------
__global__ __launch_bounds__(256) void conv_mfma(ushort* __restrict__ hbuf,
                                                 const ushort* __restrict__ wb,
                                                 float onemb, float beta) {
  __shared__ ushort hs[64][136];
  __shared__ ushort ws[128][136];
  int tid = threadIdx.x;
  size_t row0 = (size_t)blockIdx.x * 64;
#pragma unroll
  for (int i = 0; i < 4; i++) {
    int u = tid + i * 256;
    int r = u >> 4, o = u & 15;
    if (row0 + r < N_NODES)
      *(uint4*)&hs[r][o * 8] = *(const uint4*)(hbuf + (row0 + r) * HID_C + o * 8);
  }
#pragma unroll
  for (int i = 0; i < 8; i++) {
    int u = tid + i * 256;
    int c = u >> 4, o = u & 15;
    *(uint4*)&ws[c][o * 8] = *(const uint4*)(wb + (size_t)c * HID_C + o * 8);
  }
  __syncthreads();
  int lane = tid & 63;
  int wv = tid >> 6;
  int m0 = wv * 16;
  int arow = m0 + (lane & 15), akb = (lane >> 4) * 8;
  f32x4 acc[8] = {};
#pragma unroll
  for (int ks = 0; ks < 4; ks++) {
    int kk = ks * 32 + akb;
    bf16x8 a = *(bf16x8*)&hs[arow][kk];
#pragma unroll
    for (int n = 0; n < 8; n++) {
      bf16x8 b = *(bf16x8*)&ws[n * 16 + (lane & 15)][kk];
      acc[n] = __builtin_amdgcn_mfma_f32_16x16x32_bf16(a, b, acc[n], 0, 0, 0);
    }
  }
  int crow = m0 + (lane >> 4) * 4, ccol = lane & 15;
#pragma unroll
  for (int n = 0; n < 8; n++)
#pragma unroll
    for (int r = 0; r < 4; r++) {
      if (row0 + crow + r < N_NODES) {
        float hv = bflo((uint)hs[crow + r][n * 16 + ccol]);
        float o = fmaxf(onemb * hv + beta * acc[n][r], 0.f);
        hbuf[(row0 + crow + r) * HID_C + n * 16 + ccol] = f2bf(o);
      }
    }
}

// ---------------------------------------------------------------------------
// Decoder MFMA: out = h @ W_dec.T -> fp32 [N,64]
// ---------------------------------------------------------------------------
__global__ __launch_bounds__(256) void dec_mfma(const ushort* __restrict__ h,
                                                const ushort* __restrict__ wb,
                                                float* __restrict__ out) {
  __shared__ ushort hs[32][136];
  __shared__ ushort ws[64][136];
  int tid = threadIdx.x;
  size_t row0 = (size_t)blockIdx.x * 32;
  {
    int r = tid >> 3, o = tid & 7;
    *(uint4*)&hs[r][o * 16] = *(const uint4*)(h + (row0 + r) * HID_C + o * 16);
    *(uint4*)&hs[r][o * 16 + 8] = *(const uint4*)(h + (row0 + r) * HID_C + o * 16 + 8);
  }
#pragma unroll
  for (int i = 0; i < 4; i++) {
    int u = tid + i * 256;
    int c = u >> 4, o = u & 15;
    *(uint4*)&ws[c][o * 8] = *(const uint4*)(wb + (size_t)c * HID_C + o * 8);
  }
  __syncthreads();
  int lane = tid & 63, wv = tid >> 6;
  int m0 = (wv >> 1) * 16, n0 = (wv & 1) * 32;
  int arow = m0 + (lane & 15), akb = (lane >> 4) * 8;
  f32x4 acc[2] = {};
#pragma unroll
  for (int ks = 0; ks < 4; ks++) {
    int kk = ks * 32 + akb;
    bf16x8 a = *(bf16x8*)&hs[arow][kk];
#pragma unroll
    for (int n = 0; n < 2; n++) {
      bf16x8 b = *(bf16x8*)&ws[n0 + n * 16 + (lane & 15)][kk];
      acc[n] = __builtin_amdgcn_mfma_f32_16x16x32_bf16(a, b, acc[n], 0, 0, 0);
    }
  }
  int crow = m0 + (lane >> 4) * 4, ccol = lane & 15;
#pragma unroll
  for (int n = 0; n < 2; n++)
#pragma unroll
    for (int r = 0; r < 4; r++)
      out[(row0 + crow + r) * OUT_C + n0 + n * 16 + ccol] = acc[n][r];
}

// ---------------------------------------------------------------------------
extern "C" void kernel_launch(void* const* d_in, const int* in_sizes, int n_in,
                              void* d_out, int out_size, void* d_ws, size_t ws_size,
                              hipStream_t stream) {
  const float* x = (const float*)d_in[0];
  const int* ei = (const int*)d_in[1];
  const float* ew = (const float*)d_in[2];
  const float* Wenc = (const float*)d_in[3];
  const float* Wconvs = (const float*)d_in[4];
  const float* Wdec = (const float*)d_in[5];
  float* out = (float*)d_out;

  char* p = (char*)d_ws;
  ushort* H0 = (ushort*)p; p += (size_t)N_NODES * HID_C * 2;
  ushort* HA = (ushort*)p; p += (size_t)N_NODES * HID_C * 2;
  ushort* HB = (ushort*)p; p += (size_t)N_NODES * HID_C * 2;
  uint* EPK = (uint*)p;    p += (size_t)N_EDGES * 4;
  uint2* BB = (uint2*)p;   p += (size_t)128 * BINSTRIDE * 8;
  ushort* WENC = (ushort*)p;  p += 128 * 512 * 2;
  ushort* WCONV = (ushort*)p; p += 8 * 128 * 128 * 2;
  ushort* WDEC = (ushort*)p;  p += 64 * 128 * 2;
  int* ROW = (int*)p;  p += (N_NODES + 1) * 4;
  int* CNT = (int*)p;  p += N_NODES * 4;
  int* INCL = (int*)p; p += N_NODES * 4;
  int* BINCUR = (int*)p; p += 128 * 4;
  int* AUX = (int*)p;  p += 128 * 4;
  int* AUXI = (int*)p;

  const int* src = ei;
  const int* dst = ei + N_EDGES;

  // weights -> bf16 (W_convs transposed per layer)
  cast_weights<<<512, 256, 0, stream>>>(Wenc, Wconvs, Wdec, WENC, WCONV, WDEC);

  // CSR build (hist-free)
  init_bincur<<<1, 128, 0, stream>>>(BINCUR);
  bin_scatter<<<(N_EDGES + 2047) / 2048, 256, 0, stream>>>(src, dst, ew, BINCUR, BB);
  bin_count<<<98, 256, 0, stream>>>(BB, BINCUR, CNT);
  scan_block<<<98, 256, 0, stream>>>(CNT, INCL, AUX, N_NODES);
  scan_block<<<1, 256, 0, stream>>>(AUX, AUXI, nullptr, 98);
  finalize_rows<<<391, 256, 0, stream>>>(INCL, AUXI, ROW, N_NODES);
  bin_place<<<98, 256, 0, stream>>>(BB, BINCUR, ROW, EPK);

  // encoder
  enc_mfma<<<1563, 256, 0, stream>>>(x, WENC, H0);

  // layers
  const ushort* cur = H0;
  ushort* bufs[2] = {HA, HB};
  for (int i = 0; i < N_LAYERS; i++) {
    ushort* nxt = bufs[i & 1];
    agg_bf<<<25000, 256, 0, stream>>>(cur, H0, ROW, EPK, nxt);
    float beta = logf(0.5f / (float)(i + 1) + 1.0f);
    conv_mfma<<<1563, 256, 0, stream>>>(nxt, WCONV + (size_t)i * HID_C * HID_C,
                                        1.0f - beta, beta);
    cur = nxt;
  }

  // decoder
  dec_mfma<<<3125, 256, 0, stream>>>(cur, WDEC, out);
}

// Round 11
// 804.258 us; speedup vs baseline: 1.0540x; 1.0198x over previous
//
#include <hip/hip_runtime.h>
#include <math.h>

#define N_NODES 100000
#define N_EDGES 1600000
#define IN_C 512
#define HID_C 128
#define OUT_C 64
#define N_LAYERS 8
#define N_BINS 98
// edges per 1024-node bin: mean = 1.6M*1024/100000 = 16384, sigma ~127.
#define BINSTRIDE 18432

typedef short bf16x8 __attribute__((ext_vector_type(8)));
typedef float f32x4 __attribute__((ext_vector_type(4)));

static __device__ __forceinline__ ushort f2bf(float f) {
  uint u = __float_as_uint(f);
  u = (u + 0x7FFFu + ((u >> 16) & 1u)) >> 16;
  return (ushort)u;
}
static __device__ __forceinline__ float bflo(uint u) { return __uint_as_float(u << 16); }
static __device__ __forceinline__ float bfhi(uint u) { return __uint_as_float(u & 0xffff0000u); }

// ---------------------------------------------------------------------------
// CSR build:
//   init_bincur -> bin_scatter (fixed-stride dst-bins, coalesced run writes)
//   -> bin_base (98-entry scan) -> bin_finalize (count+scan+ROW+place in-block)
// ---------------------------------------------------------------------------
__global__ __launch_bounds__(128) void init_bincur(int* __restrict__ bincur) {
  bincur[threadIdx.x] = threadIdx.x * BINSTRIDE;
}

// bb entry: x = payload (w15<<17 | src17), y = full dst (bin = y>>10).
__global__ __launch_bounds__(256) void bin_scatter(const int* __restrict__ src,
                                                   const int* __restrict__ dst,
                                                   const float* __restrict__ w,
                                                   int* __restrict__ bincur,
                                                   uint2* __restrict__ bb) {
  __shared__ uint2 ebuf[2048];
  __shared__ int hist[128];
  __shared__ int lstart[128];
  __shared__ int gbase[128];
  int tid = threadIdx.x;
  int base = blockIdx.x * 2048;
  int cnt = N_EDGES - base;
  if (cnt > 2048) cnt = 2048;
  if (tid < 128) hist[tid] = 0;
  __syncthreads();
  uint pay[8];
  int bn[8], rk[8], dfull[8];
#pragma unroll
  for (int i = 0; i < 8; i++) {
    int idx = tid + i * 256;
    if (idx < cnt) {
      int e = base + idx;
      int d = dst[e];
      uint fb = __float_as_uint(w[e]) + 0x8000u;
      pay[i] = ((fb >> 16) << 17) | (uint)src[e];
      dfull[i] = d;
      bn[i] = d >> 10;
      rk[i] = atomicAdd(&hist[bn[i]], 1);
    }
  }
  __syncthreads();
  if (tid == 0) {
    int acc = 0;
    for (int b = 0; b < 128; b++) { lstart[b] = acc; acc += hist[b]; }
  }
  __syncthreads();
  if (tid < 128 && hist[tid] > 0) gbase[tid] = atomicAdd(&bincur[tid], hist[tid]);
  __syncthreads();
#pragma unroll
  for (int i = 0; i < 8; i++) {
    int idx = tid + i * 256;
    if (idx < cnt) ebuf[lstart[bn[i]] + rk[i]] = make_uint2(pay[i], (uint)dfull[i]);
  }
  __syncthreads();
#pragma unroll
  for (int i = 0; i < 8; i++) {
    int j = tid + i * 256;
    if (j < cnt) {
      uint2 v = ebuf[j];
      int b = (int)(v.y >> 10);
      bb[gbase[b] + (j - lstart[b])] = v;
    }
  }
}

// exclusive scan of per-bin totals -> global CSR base per bin (tiny)
__global__ __launch_bounds__(64) void bin_base(const int* __restrict__ bincur,
                                               int* __restrict__ base) {
  if (threadIdx.x == 0) {
    int acc = 0;
    for (int b = 0; b < N_BINS; b++) {
      base[b] = acc;
      acc += bincur[b] - b * BINSTRIDE;
    }
  }
}

// Per-bin: count (pass 1), block-scan 1024 counts, write ROW, place (pass 2).
__global__ __launch_bounds__(256) void bin_finalize(const uint2* __restrict__ bb,
                                                    const int* __restrict__ bincur,
                                                    const int* __restrict__ base,
                                                    int* __restrict__ row,
                                                    uint* __restrict__ epk) {
  __shared__ int lc[1024];
  __shared__ int tsum[256];
  int b = blockIdx.x, tid = threadIdx.x;
  int n0 = b << 10;
  for (int i = tid; i < 1024; i += 256) lc[i] = 0;
  __syncthreads();
  int beg = b * BINSTRIDE, end = bincur[b];
  for (int j = beg + tid; j < end; j += 256)
    atomicAdd(&lc[bb[j].y & 1023u], 1);
  __syncthreads();
  // block scan (4 counts per thread)
  int i0 = tid * 4;
  int v0 = lc[i0], v1 = lc[i0 + 1], v2 = lc[i0 + 2], v3 = lc[i0 + 3];
  int s = v0 + v1 + v2 + v3;
  tsum[tid] = s;
  __syncthreads();
  for (int off = 1; off < 256; off <<= 1) {
    int xx = (tid >= off) ? tsum[tid - off] : 0;
    __syncthreads();
    tsum[tid] += xx;
    __syncthreads();
  }
  int excl = tsum[tid] - s;
  int gb = base[b];
  int e0 = gb + excl, e1 = e0 + v0, e2 = e1 + v1, e3 = e2 + v2;
  // cursors (same-thread slots; no cross-thread hazard)
  lc[i0] = e0; lc[i0 + 1] = e1; lc[i0 + 2] = e2; lc[i0 + 3] = e3;
  // ROW
  if (n0 + i0 + 0 < N_NODES) row[n0 + i0 + 0] = e0;
  if (n0 + i0 + 1 < N_NODES) row[n0 + i0 + 1] = e1;
  if (n0 + i0 + 2 < N_NODES) row[n0 + i0 + 2] = e2;
  if (n0 + i0 + 3 < N_NODES) row[n0 + i0 + 3] = e3;
  if (b == ((N_NODES - 1) >> 10) && tid == 255) row[N_NODES] = gb + tsum[255];
  __syncthreads();
  for (int j = beg + tid; j < end; j += 256) {
    uint2 v = bb[j];
    int p = atomicAdd(&lc[v.y & 1023u], 1);
    epk[p] = v.x;
  }
}

// ---------------------------------------------------------------------------
// Pre-cast weights fp32 -> bf16 (W_convs transposed per layer)
// ---------------------------------------------------------------------------
__global__ __launch_bounds__(256) void cast_weights(const float* __restrict__ we,
                                                    const float* __restrict__ wc,
                                                    const float* __restrict__ wd,
                                                    ushort* __restrict__ web,
                                                    ushort* __restrict__ wcb,
                                                    ushort* __restrict__ wdb) {
  int i = blockIdx.x * 256 + threadIdx.x;
  if (i < 128 * 512) web[i] = f2bf(we[i]);
  if (i < 8 * 128 * 128) {
    int layer = i >> 14, rem = i & 16383, k = rem >> 7, j = rem & 127;
    wcb[(layer << 14) + (j << 7) + k] = f2bf(wc[i]);  // wcb[l][j][k] = W[l][k][j]
  }
  if (i < 64 * 128) wdb[i] = f2bf(wd[i]);
}

// ---------------------------------------------------------------------------
// Encoder MFMA, 64 rows/block: h = x @ W_enc.T
// ---------------------------------------------------------------------------
__global__ __launch_bounds__(256) void enc_mfma(const float* __restrict__ x,
                                                const ushort* __restrict__ wb,
                                                ushort* __restrict__ h) {
  __shared__ ushort xs[64][136];
  __shared__ ushort ws[128][136];
  int tid = threadIdx.x;
  size_t row0 = (size_t)blockIdx.x * 64;
  int lane = tid & 63;
  int wv = tid >> 6;
  int m0 = (wv >> 1) * 32;
  int n0 = (wv & 1) * 64;
  int arow = m0 + (lane & 15);
  int akb = (lane >> 4) * 8;
  f32x4 acc[2][4] = {};
  for (int kc = 0; kc < 4; kc++) {
    int k0 = kc * 128;
    __syncthreads();
#pragma unroll
    for (int i = 0; i < 8; i++) {
      int u = tid + i * 256;
      int r = u >> 5, c4 = u & 31;
      uint2 p = make_uint2(0u, 0u);
      if (row0 + r < N_NODES) {
        float4 v = *(const float4*)(x + (row0 + r) * IN_C + k0 + c4 * 4);
        p.x = (uint)f2bf(v.x) | ((uint)f2bf(v.y) << 16);
        p.y = (uint)f2bf(v.z) | ((uint)f2bf(v.w) << 16);
      }
      *(uint2*)&xs[r][c4 * 4] = p;
    }
#pragma unroll
    for (int i = 0; i < 8; i++) {
      int u = tid + i * 256;
      int c = u >> 4, o = u & 15;
      *(uint4*)&ws[c][o * 8] = *(const uint4*)(wb + (size_t)c * IN_C + k0 + o * 8);
    }
    __syncthreads();
#pragma unroll
    for (int ks = 0; ks < 4; ks++) {
      int kk = ks * 32 + akb;
      bf16x8 a0 = *(bf16x8*)&xs[arow][kk];
      bf16x8 a1 = *(bf16x8*)&xs[arow + 16][kk];
#pragma unroll
      for (int n = 0; n < 4; n++) {
        bf16x8 b = *(bf16x8*)&ws[n0 + n * 16 + (lane & 15)][kk];
        acc[0][n] = __builtin_amdgcn_mfma_f32_16x16x32_bf16(a0, b, acc[0][n], 0, 0, 0);
        acc[1][n] = __builtin_amdgcn_mfma_f32_16x16x32_bf16(a1, b, acc[1][n], 0, 0, 0);
      }
    }
  }
  int crow = m0 + (lane >> 4) * 4;
  int ccol = lane & 15;
#pragma unroll
  for (int m = 0; m < 2; m++)
#pragma unroll
    for (int n = 0; n < 4; n++)
#pragma unroll
      for (int r = 0; r < 4; r++) {
        size_t rr = row0 + crow + m * 16 + r;
        if (rr < N_NODES)
          h[rr * HID_C + n0 + n * 16 + ccol] = f2bf(acc[m][n][r]);
      }
}

// ---------------------------------------------------------------------------
// Aggregation: hh[n] = 0.9*sum w_e*h[src_e] + 0.1*x0[n]
// One wave per node, lane = 2 channels, masked 8-deep batches (MLP=8).
// ---------------------------------------------------------------------------
__global__ __launch_bounds__(256) void agg_bf(const ushort* __restrict__ h,
                                              const ushort* __restrict__ x0,
                                              const int* __restrict__ row,
                                              const uint* __restrict__ epk,
                                              ushort* __restrict__ out) {
  int node = (blockIdx.x * 256 + threadIdx.x) >> 6;
  int lane = threadIdx.x & 63;
  int beg = row[node], end = row[node + 1];
  float a0 = 0.f, a1 = 0.f;
  const uint* hp = (const uint*)h + lane;  // h row = 64 uints
  for (int e = beg; e < end; e += 8) {
    uint p0 = (e + 0 < end) ? epk[e + 0] : 0u;
    uint p1 = (e + 1 < end) ? epk[e + 1] : 0u;
    uint p2 = (e + 2 < end) ? epk[e + 2] : 0u;
    uint p3 = (e + 3 < end) ? epk[e + 3] : 0u;
    uint p4 = (e + 4 < end) ? epk[e + 4] : 0u;
    uint p5 = (e + 5 < end) ? epk[e + 5] : 0u;
    uint p6 = (e + 6 < end) ? epk[e + 6] : 0u;
    uint p7 = (e + 7 < end) ? epk[e + 7] : 0u;
    uint h0 = hp[(size_t)(p0 & 0x1FFFFu) * 64];
    uint h1 = hp[(size_t)(p1 & 0x1FFFFu) * 64];
    uint h2 = hp[(size_t)(p2 & 0x1FFFFu) * 64];
    uint h3 = hp[(size_t)(p3 & 0x1FFFFu) * 64];
    uint h4 = hp[(size_t)(p4 & 0x1FFFFu) * 64];
    uint h5 = hp[(size_t)(p5 & 0x1FFFFu) * 64];
    uint h6 = hp[(size_t)(p6 & 0x1FFFFu) * 64];
    uint h7 = hp[(size_t)(p7 & 0x1FFFFu) * 64];
    float w0 = __uint_as_float((p0 >> 17) << 16);
    float w1 = __uint_as_float((p1 >> 17) << 16);
    float w2 = __uint_as_float((p2 >> 17) << 16);
    float w3 = __uint_as_float((p3 >> 17) << 16);
    float w4 = __uint_as_float((p4 >> 17) << 16);
    float w5 = __uint_as_float((p5 >> 17) << 16);
    float w6 = __uint_as_float((p6 >> 17) << 16);
    float w7 = __uint_as_float((p7 >> 17) << 16);
    a0 = fmaf(w0, bflo(h0), a0); a1 = fmaf(w0, bfhi(h0), a1);
    a0 = fmaf(w1, bflo(h1), a0); a1 = fmaf(w1, bfhi(h1), a1);
    a0 = fmaf(w2, bflo(h2), a0); a1 = fmaf(w2, bfhi(h2), a1);
    a0 = fmaf(w3, bflo(h3), a0); a1 = fmaf(w3, bfhi(h3), a1);
    a0 = fmaf(w4, bflo(h4), a0); a1 = fmaf(w4, bfhi(h4), a1);
    a0 = fmaf(w5, bflo(h5), a0); a1 = fmaf(w5, bfhi(h5), a1);
    a0 = fmaf(w6, bflo(h6), a0); a1 = fmaf(w6, bfhi(h6), a1);
    a0 = fmaf(w7, bflo(h7), a0); a1 = fmaf(w7, bfhi(h7), a1);
  }
  uint xv = ((const uint*)x0)[(size_t)node * 64 + lane];
  float o0 = 0.9f * a0 + 0.1f * bflo(xv);
  float o1 = 0.9f * a1 + 0.1f * bfhi(xv);
  ((uint*)out)[(size_t)node * 64 + lane] = (uint)f2bf(o0) | ((uint)f2bf(o1) << 16);
}

// ---------------------------------------------------------------------------
// Conv MFMA (in-place), 64 rows/block: h = relu((1-b)*hh + b*(hh @ W))
// ---------------------------------------------------------------------------
__global__ __launch_bounds__(256) void conv_mfma(ushort* __restrict__ hbuf,
                                                 const ushort* __restrict__ wb,
                                                 float onemb, float beta) {
  __shared__ ushort hs[64][136];
  __shared__ ushort ws[128][136];
  int tid = threadIdx.x;
  size_t row0 = (size_t)blockIdx.x * 64;
#pragma unroll
  for (int i = 0; i < 4; i++) {
    int u = tid + i * 256;
    int r = u >> 4, o = u & 15;
    if (row0 + r < N_NODES)
      *(uint4*)&hs[r][o * 8] = *(const uint4*)(hbuf + (row0 + r) * HID_C + o * 8);
  }
#pragma unroll
  for (int i = 0; i < 8; i++) {
    int u = tid + i * 256;
    int c = u >> 4, o = u & 15;
    *(uint4*)&ws[c][o * 8] = *(const uint4*)(wb + (size_t)c * HID_C + o * 8);
  }
  __syncthreads();
  int lane = tid & 63;
  int wv = tid >> 6;
  int m0 = wv * 16;
  int arow = m0 + (lane & 15), akb = (lane >> 4) * 8;
  f32x4 acc[8] = {};
#pragma unroll
  for (int ks = 0; ks < 4; ks++) {
    int kk = ks * 32 + akb;
    bf16x8 a = *(bf16x8*)&hs[arow][kk];
#pragma unroll
    for (int n = 0; n < 8; n++) {
      bf16x8 b = *(bf16x8*)&ws[n * 16 + (lane & 15)][kk];
      acc[n] = __builtin_amdgcn_mfma_f32_16x16x32_bf16(a, b, acc[n], 0, 0, 0);
    }
  }
  int crow = m0 + (lane >> 4) * 4, ccol = lane & 15;
#pragma unroll
  for (int n = 0; n < 8; n++)
#pragma unroll
    for (int r = 0; r < 4; r++) {
      if (row0 + crow + r < N_NODES) {
        float hv = bflo((uint)hs[crow + r][n * 16 + ccol]);
        float o = fmaxf(onemb * hv + beta * acc[n][r], 0.f);
        hbuf[(row0 + crow + r) * HID_C + n * 16 + ccol] = f2bf(o);
      }
    }
}

// ---------------------------------------------------------------------------
// Decoder MFMA: out = h @ W_dec.T -> fp32 [N,64]
// ---------------------------------------------------------------------------
__global__ __launch_bounds__(256) void dec_mfma(const ushort* __restrict__ h,
                                                const ushort* __restrict__ wb,
                                                float* __restrict__ out) {
  __shared__ ushort hs[32][136];
  __shared__ ushort ws[64][136];
  int tid = threadIdx.x;
  size_t row0 = (size_t)blockIdx.x * 32;
  {
    int r = tid >> 3, o = tid & 7;
    *(uint4*)&hs[r][o * 16] = *(const uint4*)(h + (row0 + r) * HID_C + o * 16);
    *(uint4*)&hs[r][o * 16 + 8] = *(const uint4*)(h + (row0 + r) * HID_C + o * 16 + 8);
  }
#pragma unroll
  for (int i = 0; i < 4; i++) {
    int u = tid + i * 256;
    int c = u >> 4, o = u & 15;
    *(uint4*)&ws[c][o * 8] = *(const uint4*)(wb + (size_t)c * HID_C + o * 8);
  }
  __syncthreads();
  int lane = tid & 63, wv = tid >> 6;
  int m0 = (wv >> 1) * 16, n0 = (wv & 1) * 32;
  int arow = m0 + (lane & 15), akb = (lane >> 4) * 8;
  f32x4 acc[2] = {};
#pragma unroll
  for (int ks = 0; ks < 4; ks++) {
    int kk = ks * 32 + akb;
    bf16x8 a = *(bf16x8*)&hs[arow][kk];
#pragma unroll
    for (int n = 0; n < 2; n++) {
      bf16x8 b = *(bf16x8*)&ws[n0 + n * 16 + (lane & 15)][kk];
      acc[n] = __builtin_amdgcn_mfma_f32_16x16x32_bf16(a, b, acc[n], 0, 0, 0);
    }
  }
  int crow = m0 + (lane >> 4) * 4, ccol = lane & 15;
#pragma unroll
  for (int n = 0; n < 2; n++)
#pragma unroll
    for (int r = 0; r < 4; r++)
      out[(row0 + crow + r) * OUT_C + n0 + n * 16 + ccol] = acc[n][r];
}

// ---------------------------------------------------------------------------
extern "C" void kernel_launch(void* const* d_in, const int* in_sizes, int n_in,
                              void* d_out, int out_size, void* d_ws, size_t ws_size,
                              hipStream_t stream) {
  const float* x = (const float*)d_in[0];
  const int* ei = (const int*)d_in[1];
  const float* ew = (const float*)d_in[2];
  const float* Wenc = (const float*)d_in[3];
  const float* Wconvs = (const float*)d_in[4];
  const float* Wdec = (const float*)d_in[5];
  float* out = (float*)d_out;

  char* p = (char*)d_ws;
  ushort* H0 = (ushort*)p; p += (size_t)N_NODES * HID_C * 2;
  ushort* HA = (ushort*)p; p += (size_t)N_NODES * HID_C * 2;
  ushort* HB = (ushort*)p; p += (size_t)N_NODES * HID_C * 2;
  uint* EPK = (uint*)p;    p += (size_t)N_EDGES * 4;
  uint2* BB = (uint2*)p;   p += (size_t)128 * BINSTRIDE * 8;
  ushort* WENC = (ushort*)p;  p += 128 * 512 * 2;
  ushort* WCONV = (ushort*)p; p += 8 * 128 * 128 * 2;
  ushort* WDEC = (ushort*)p;  p += 64 * 128 * 2;
  int* ROW = (int*)p;  p += (N_NODES + 1) * 4;
  int* BINCUR = (int*)p; p += 128 * 4;
  int* BASE = (int*)p;   p += 128 * 4;

  const int* src = ei;
  const int* dst = ei + N_EDGES;

  // weights -> bf16 (W_convs transposed per layer)
  cast_weights<<<512, 256, 0, stream>>>(Wenc, Wconvs, Wdec, WENC, WCONV, WDEC);

  // CSR build
  init_bincur<<<1, 128, 0, stream>>>(BINCUR);
  bin_scatter<<<(N_EDGES + 2047) / 2048, 256, 0, stream>>>(src, dst, ew, BINCUR, BB);
  bin_base<<<1, 64, 0, stream>>>(BINCUR, BASE);
  bin_finalize<<<N_BINS, 256, 0, stream>>>(BB, BINCUR, BASE, ROW, EPK);

  // encoder
  enc_mfma<<<1563, 256, 0, stream>>>(x, WENC, H0);

  // layers
  const ushort* cur = H0;
  ushort* bufs[2] = {HA, HB};
  for (int i = 0; i < N_LAYERS; i++) {
    ushort* nxt = bufs[i & 1];
    agg_bf<<<25000, 256, 0, stream>>>(cur, H0, ROW, EPK, nxt);
    float beta = logf(0.5f / (float)(i + 1) + 1.0f);
    conv_mfma<<<1563, 256, 0, stream>>>(nxt, WCONV + (size_t)i * HID_C * HID_C,
                                        1.0f - beta, beta);
    cur = nxt;
  }

  // decoder
  dec_mfma<<<3125, 256, 0, stream>>>(cur, WDEC, out);
}

// Round 12
// 802.491 us; speedup vs baseline: 1.0563x; 1.0022x over previous
//
#include <hip/hip_runtime.h>
#include <math.h>

#define N_NODES 100000
#define N_EDGES 1600000
#define IN_C 512
#define HID_C 128
#define OUT_C 64
#define N_LAYERS 8
#define N_BINS 98
// edges per 1024-node bin: mean = 1.6M*1024/100000 = 16384, sigma ~127.
#define BINSTRIDE 18432

typedef short bf16x8 __attribute__((ext_vector_type(8)));
typedef float f32x4 __attribute__((ext_vector_type(4)));

static __device__ __forceinline__ ushort f2bf(float f) {
  uint u = __float_as_uint(f);
  u = (u + 0x7FFFu + ((u >> 16) & 1u)) >> 16;
  return (ushort)u;
}
static __device__ __forceinline__ float bflo(uint u) { return __uint_as_float(u << 16); }
static __device__ __forceinline__ float bfhi(uint u) { return __uint_as_float(u & 0xffff0000u); }

// ---------------------------------------------------------------------------
// CSR build:
//   init_bincur -> bin_scatter (fixed-stride dst-bins, coalesced run writes)
//   -> bin_base (98-entry scan) -> bin_finalize (count+scan+ROW+place in-block)
// ---------------------------------------------------------------------------
__global__ __launch_bounds__(128) void init_bincur(int* __restrict__ bincur) {
  bincur[threadIdx.x] = threadIdx.x * BINSTRIDE;
}

// bb entry: x = payload (w15<<17 | src17), y = full dst (bin = y>>10).
__global__ __launch_bounds__(256) void bin_scatter(const int* __restrict__ src,
                                                   const int* __restrict__ dst,
                                                   const float* __restrict__ w,
                                                   int* __restrict__ bincur,
                                                   uint2* __restrict__ bb) {
  __shared__ uint2 ebuf[2048];
  __shared__ int hist[128];
  __shared__ int lstart[128];
  __shared__ int gbase[128];
  int tid = threadIdx.x;
  int base = blockIdx.x * 2048;
  int cnt = N_EDGES - base;
  if (cnt > 2048) cnt = 2048;
  if (tid < 128) hist[tid] = 0;
  __syncthreads();
  uint pay[8];
  int bn[8], rk[8], dfull[8];
#pragma unroll
  for (int i = 0; i < 8; i++) {
    int idx = tid + i * 256;
    if (idx < cnt) {
      int e = base + idx;
      int d = dst[e];
      uint fb = __float_as_uint(w[e]) + 0x8000u;
      pay[i] = ((fb >> 16) << 17) | (uint)src[e];
      dfull[i] = d;
      bn[i] = d >> 10;
      rk[i] = atomicAdd(&hist[bn[i]], 1);
    }
  }
  __syncthreads();
  if (tid == 0) {
    int acc = 0;
    for (int b = 0; b < 128; b++) { lstart[b] = acc; acc += hist[b]; }
  }
  __syncthreads();
  if (tid < 128 && hist[tid] > 0) gbase[tid] = atomicAdd(&bincur[tid], hist[tid]);
  __syncthreads();
#pragma unroll
  for (int i = 0; i < 8; i++) {
    int idx = tid + i * 256;
    if (idx < cnt) ebuf[lstart[bn[i]] + rk[i]] = make_uint2(pay[i], (uint)dfull[i]);
  }
  __syncthreads();
#pragma unroll
  for (int i = 0; i < 8; i++) {
    int j = tid + i * 256;
    if (j < cnt) {
      uint2 v = ebuf[j];
      int b = (int)(v.y >> 10);
      bb[gbase[b] + (j - lstart[b])] = v;
    }
  }
}

// exclusive scan of per-bin totals -> global CSR base per bin (tiny)
__global__ __launch_bounds__(64) void bin_base(const int* __restrict__ bincur,
                                               int* __restrict__ base) {
  if (threadIdx.x == 0) {
    int acc = 0;
    for (int b = 0; b < N_BINS; b++) {
      base[b] = acc;
      acc += bincur[b] - b * BINSTRIDE;
    }
  }
}

// Per-bin: count (pass 1), block-scan 1024 counts, write ROW, place (pass 2).
__global__ __launch_bounds__(256) void bin_finalize(const uint2* __restrict__ bb,
                                                    const int* __restrict__ bincur,
                                                    const int* __restrict__ base,
                                                    int* __restrict__ row,
                                                    uint* __restrict__ epk) {
  __shared__ int lc[1024];
  __shared__ int tsum[256];
  int b = blockIdx.x, tid = threadIdx.x;
  int n0 = b << 10;
  for (int i = tid; i < 1024; i += 256) lc[i] = 0;
  __syncthreads();
  int beg = b * BINSTRIDE, end = bincur[b];
  for (int j = beg + tid; j < end; j += 256)
    atomicAdd(&lc[bb[j].y & 1023u], 1);
  __syncthreads();
  int i0 = tid * 4;
  int v0 = lc[i0], v1 = lc[i0 + 1], v2 = lc[i0 + 2], v3 = lc[i0 + 3];
  int s = v0 + v1 + v2 + v3;
  tsum[tid] = s;
  __syncthreads();
  for (int off = 1; off < 256; off <<= 1) {
    int xx = (tid >= off) ? tsum[tid - off] : 0;
    __syncthreads();
    tsum[tid] += xx;
    __syncthreads();
  }
  int excl = tsum[tid] - s;
  int gb = base[b];
  int e0 = gb + excl, e1 = e0 + v0, e2 = e1 + v1, e3 = e2 + v2;
  lc[i0] = e0; lc[i0 + 1] = e1; lc[i0 + 2] = e2; lc[i0 + 3] = e3;
  if (n0 + i0 + 0 < N_NODES) row[n0 + i0 + 0] = e0;
  if (n0 + i0 + 1 < N_NODES) row[n0 + i0 + 1] = e1;
  if (n0 + i0 + 2 < N_NODES) row[n0 + i0 + 2] = e2;
  if (n0 + i0 + 3 < N_NODES) row[n0 + i0 + 3] = e3;
  if (b == ((N_NODES - 1) >> 10) && tid == 255) row[N_NODES] = gb + tsum[255];
  __syncthreads();
  for (int j = beg + tid; j < end; j += 256) {
    uint2 v = bb[j];
    int p = atomicAdd(&lc[v.y & 1023u], 1);
    epk[p] = v.x;
  }
}

// ---------------------------------------------------------------------------
// Pre-cast weights fp32 -> bf16 (W_convs transposed per layer)
// ---------------------------------------------------------------------------
__global__ __launch_bounds__(256) void cast_weights(const float* __restrict__ we,
                                                    const float* __restrict__ wc,
                                                    const float* __restrict__ wd,
                                                    ushort* __restrict__ web,
                                                    ushort* __restrict__ wcb,
                                                    ushort* __restrict__ wdb) {
  int i = blockIdx.x * 256 + threadIdx.x;
  if (i < 128 * 512) web[i] = f2bf(we[i]);
  if (i < 8 * 128 * 128) {
    int layer = i >> 14, rem = i & 16383, k = rem >> 7, j = rem & 127;
    wcb[(layer << 14) + (j << 7) + k] = f2bf(wc[i]);  // wcb[l][j][k] = W[l][k][j]
  }
  if (i < 64 * 128) wdb[i] = f2bf(wd[i]);
}

// ---------------------------------------------------------------------------
// Encoder MFMA, 64 rows/block: h = x @ W_enc.T
// ---------------------------------------------------------------------------
__global__ __launch_bounds__(256) void enc_mfma(const float* __restrict__ x,
                                                const ushort* __restrict__ wb,
                                                ushort* __restrict__ h) {
  __shared__ ushort xs[64][136];
  __shared__ ushort ws[128][136];
  int tid = threadIdx.x;
  size_t row0 = (size_t)blockIdx.x * 64;
  int lane = tid & 63;
  int wv = tid >> 6;
  int m0 = (wv >> 1) * 32;
  int n0 = (wv & 1) * 64;
  int arow = m0 + (lane & 15);
  int akb = (lane >> 4) * 8;
  f32x4 acc[2][4] = {};
  for (int kc = 0; kc < 4; kc++) {
    int k0 = kc * 128;
    __syncthreads();
#pragma unroll
    for (int i = 0; i < 8; i++) {
      int u = tid + i * 256;
      int r = u >> 5, c4 = u & 31;
      uint2 p = make_uint2(0u, 0u);
      if (row0 + r < N_NODES) {
        float4 v = *(const float4*)(x + (row0 + r) * IN_C + k0 + c4 * 4);
        p.x = (uint)f2bf(v.x) | ((uint)f2bf(v.y) << 16);
        p.y = (uint)f2bf(v.z) | ((uint)f2bf(v.w) << 16);
      }
      *(uint2*)&xs[r][c4 * 4] = p;
    }
#pragma unroll
    for (int i = 0; i < 8; i++) {
      int u = tid + i * 256;
      int c = u >> 4, o = u & 15;
      *(uint4*)&ws[c][o * 8] = *(const uint4*)(wb + (size_t)c * IN_C + k0 + o * 8);
    }
    __syncthreads();
#pragma unroll
    for (int ks = 0; ks < 4; ks++) {
      int kk = ks * 32 + akb;
      bf16x8 a0 = *(bf16x8*)&xs[arow][kk];
      bf16x8 a1 = *(bf16x8*)&xs[arow + 16][kk];
#pragma unroll
      for (int n = 0; n < 4; n++) {
        bf16x8 b = *(bf16x8*)&ws[n0 + n * 16 + (lane & 15)][kk];
        acc[0][n] = __builtin_amdgcn_mfma_f32_16x16x32_bf16(a0, b, acc[0][n], 0, 0, 0);
        acc[1][n] = __builtin_amdgcn_mfma_f32_16x16x32_bf16(a1, b, acc[1][n], 0, 0, 0);
      }
    }
  }
  int crow = m0 + (lane >> 4) * 4;
  int ccol = lane & 15;
#pragma unroll
  for (int m = 0; m < 2; m++)
#pragma unroll
    for (int n = 0; n < 4; n++)
#pragma unroll
      for (int r = 0; r < 4; r++) {
        size_t rr = row0 + crow + m * 16 + r;
        if (rr < N_NODES)
          h[rr * HID_C + n0 + n * 16 + ccol] = f2bf(acc[m][n][r]);
      }
}

// ---------------------------------------------------------------------------
// Aggregation, dual-edge lanes: hh[n] = 0.9*sum w_e*h[src_e] + 0.1*x0[n]
// One wave per node. Half-wave 0 (lanes 0-31) handles even edges, half-wave 1
// odd edges; each lane loads uint2 (4 channels) so one instruction fetches TWO
// 256B rows. 8-deep batches => 16 edges in flight. Combine via shfl_xor(32).
// ---------------------------------------------------------------------------
__global__ __launch_bounds__(256) void agg_bf(const ushort* __restrict__ h,
                                              const ushort* __restrict__ x0,
                                              const int* __restrict__ row,
                                              const uint* __restrict__ epk,
                                              ushort* __restrict__ out) {
  int node = (blockIdx.x * 256 + threadIdx.x) >> 6;
  int lane = threadIdx.x & 63;
  int half = lane >> 5;   // 0: even edges, 1: odd edges
  int cl = lane & 31;     // uint2 index within row (4 channels: 4cl..4cl+3)
  int beg = row[node], end = row[node + 1];
  float a0 = 0.f, a1 = 0.f, a2 = 0.f, a3 = 0.f;
  const uint2* hp = (const uint2*)h + cl;  // row = 32 uint2
  for (int e0 = beg; e0 < end; e0 += 16) {
    uint pv[8];
    uint2 hv[8];
#pragma unroll
    for (int k = 0; k < 8; k++) {
      int ee = e0 + 2 * k + half;
      pv[k] = (ee < end) ? epk[ee] : 0u;
    }
#pragma unroll
    for (int k = 0; k < 8; k++) hv[k] = hp[(size_t)(pv[k] & 0x1FFFFu) * 32];
#pragma unroll
    for (int k = 0; k < 8; k++) {
      float w = __uint_as_float((pv[k] >> 17) << 16);
      a0 = fmaf(w, bflo(hv[k].x), a0);
      a1 = fmaf(w, bfhi(hv[k].x), a1);
      a2 = fmaf(w, bflo(hv[k].y), a2);
      a3 = fmaf(w, bfhi(hv[k].y), a3);
    }
  }
  // combine the two half-wave partial sums (lane l <-> l^32 hold same channels)
  a0 += __shfl_xor(a0, 32);
  a1 += __shfl_xor(a1, 32);
  a2 += __shfl_xor(a2, 32);
  a3 += __shfl_xor(a3, 32);
  if (half == 0) {
    uint2 xv = ((const uint2*)x0)[(size_t)node * 32 + cl];
    float o0 = 0.9f * a0 + 0.1f * bflo(xv.x);
    float o1 = 0.9f * a1 + 0.1f * bfhi(xv.x);
    float o2 = 0.9f * a2 + 0.1f * bflo(xv.y);
    float o3 = 0.9f * a3 + 0.1f * bfhi(xv.y);
    uint2 pk;
    pk.x = (uint)f2bf(o0) | ((uint)f2bf(o1) << 16);
    pk.y = (uint)f2bf(o2) | ((uint)f2bf(o3) << 16);
    ((uint2*)out)[(size_t)node * 32 + cl] = pk;
  }
}

// ---------------------------------------------------------------------------
// Conv MFMA (in-place), 64 rows/block: h = relu((1-b)*hh + b*(hh @ W))
// ---------------------------------------------------------------------------
__global__ __launch_bounds__(256) void conv_mfma(ushort* __restrict__ hbuf,
                                                 const ushort* __restrict__ wb,
                                                 float onemb, float beta) {
  __shared__ ushort hs[64][136];
  __shared__ ushort ws[128][136];
  int tid = threadIdx.x;
  size_t row0 = (size_t)blockIdx.x * 64;
#pragma unroll
  for (int i = 0; i < 4; i++) {
    int u = tid + i * 256;
    int r = u >> 4, o = u & 15;
    if (row0 + r < N_NODES)
      *(uint4*)&hs[r][o * 8] = *(const uint4*)(hbuf + (row0 + r) * HID_C + o * 8);
  }
#pragma unroll
  for (int i = 0; i < 8; i++) {
    int u = tid + i * 256;
    int c = u >> 4, o = u & 15;
    *(uint4*)&ws[c][o * 8] = *(const uint4*)(wb + (size_t)c * HID_C + o * 8);
  }
  __syncthreads();
  int lane = tid & 63;
  int wv = tid >> 6;
  int m0 = wv * 16;
  int arow = m0 + (lane & 15), akb = (lane >> 4) * 8;
  f32x4 acc[8] = {};
#pragma unroll
  for (int ks = 0; ks < 4; ks++) {
    int kk = ks * 32 + akb;
    bf16x8 a = *(bf16x8*)&hs[arow][kk];
#pragma unroll
    for (int n = 0; n < 8; n++) {
      bf16x8 b = *(bf16x8*)&ws[n * 16 + (lane & 15)][kk];
      acc[n] = __builtin_amdgcn_mfma_f32_16x16x32_bf16(a, b, acc[n], 0, 0, 0);
    }
  }
  int crow = m0 + (lane >> 4) * 4, ccol = lane & 15;
#pragma unroll
  for (int n = 0; n < 8; n++)
#pragma unroll
    for (int r = 0; r < 4; r++) {
      if (row0 + crow + r < N_NODES) {
        float hv = bflo((uint)hs[crow + r][n * 16 + ccol]);
        float o = fmaxf(onemb * hv + beta * acc[n][r], 0.f);
        hbuf[(row0 + crow + r) * HID_C + n * 16 + ccol] = f2bf(o);
      }
    }
}

// ---------------------------------------------------------------------------
// Decoder MFMA: out = h @ W_dec.T -> fp32 [N,64]
// ---------------------------------------------------------------------------
__global__ __launch_bounds__(256) void dec_mfma(const ushort* __restrict__ h,
                                                const ushort* __restrict__ wb,
                                                float* __restrict__ out) {
  __shared__ ushort hs[32][136];
  __shared__ ushort ws[64][136];
  int tid = threadIdx.x;
  size_t row0 = (size_t)blockIdx.x * 32;
  {
    int r = tid >> 3, o = tid & 7;
    *(uint4*)&hs[r][o * 16] = *(const uint4*)(h + (row0 + r) * HID_C + o * 16);
    *(uint4*)&hs[r][o * 16 + 8] = *(const uint4*)(h + (row0 + r) * HID_C + o * 16 + 8);
  }
#pragma unroll
  for (int i = 0; i < 4; i++) {
    int u = tid + i * 256;
    int c = u >> 4, o = u & 15;
    *(uint4*)&ws[c][o * 8] = *(const uint4*)(wb + (size_t)c * HID_C + o * 8);
  }
  __syncthreads();
  int lane = tid & 63, wv = tid >> 6;
  int m0 = (wv >> 1) * 16, n0 = (wv & 1) * 32;
  int arow = m0 + (lane & 15), akb = (lane >> 4) * 8;
  f32x4 acc[2] = {};
#pragma unroll
  for (int ks = 0; ks < 4; ks++) {
    int kk = ks * 32 + akb;
    bf16x8 a = *(bf16x8*)&hs[arow][kk];
#pragma unroll
    for (int n = 0; n < 2; n++) {
      bf16x8 b = *(bf16x8*)&ws[n0 + n * 16 + (lane & 15)][kk];
      acc[n] = __builtin_amdgcn_mfma_f32_16x16x32_bf16(a, b, acc[n], 0, 0, 0);
    }
  }
  int crow = m0 + (lane >> 4) * 4, ccol = lane & 15;
#pragma unroll
  for (int n = 0; n < 2; n++)
#pragma unroll
    for (int r = 0; r < 4; r++)
      out[(row0 + crow + r) * OUT_C + n0 + n * 16 + ccol] = acc[n][r];
}

// ---------------------------------------------------------------------------
extern "C" void kernel_launch(void* const* d_in, const int* in_sizes, int n_in,
                              void* d_out, int out_size, void* d_ws, size_t ws_size,
                              hipStream_t stream) {
  const float* x = (const float*)d_in[0];
  const int* ei = (const int*)d_in[1];
  const float* ew = (const float*)d_in[2];
  const float* Wenc = (const float*)d_in[3];
  const float* Wconvs = (const float*)d_in[4];
  const float* Wdec = (const float*)d_in[5];
  float* out = (float*)d_out;

  char* p = (char*)d_ws;
  ushort* H0 = (ushort*)p; p += (size_t)N_NODES * HID_C * 2;
  ushort* HA = (ushort*)p; p += (size_t)N_NODES * HID_C * 2;
  ushort* HB = (ushort*)p; p += (size_t)N_NODES * HID_C * 2;
  uint* EPK = (uint*)p;    p += (size_t)N_EDGES * 4;
  uint2* BB = (uint2*)p;   p += (size_t)128 * BINSTRIDE * 8;
  ushort* WENC = (ushort*)p;  p += 128 * 512 * 2;
  ushort* WCONV = (ushort*)p; p += 8 * 128 * 128 * 2;
  ushort* WDEC = (ushort*)p;  p += 64 * 128 * 2;
  int* ROW = (int*)p;  p += (N_NODES + 1) * 4;
  int* BINCUR = (int*)p; p += 128 * 4;
  int* BASE = (int*)p;   p += 128 * 4;

  const int* src = ei;
  const int* dst = ei + N_EDGES;

  // weights -> bf16 (W_convs transposed per layer)
  cast_weights<<<512, 256, 0, stream>>>(Wenc, Wconvs, Wdec, WENC, WCONV, WDEC);

  // CSR build
  init_bincur<<<1, 128, 0, stream>>>(BINCUR);
  bin_scatter<<<(N_EDGES + 2047) / 2048, 256, 0, stream>>>(src, dst, ew, BINCUR, BB);
  bin_base<<<1, 64, 0, stream>>>(BINCUR, BASE);
  bin_finalize<<<N_BINS, 256, 0, stream>>>(BB, BINCUR, BASE, ROW, EPK);

  // encoder
  enc_mfma<<<1563, 256, 0, stream>>>(x, WENC, H0);

  // layers
  const ushort* cur = H0;
  ushort* bufs[2] = {HA, HB};
  for (int i = 0; i < N_LAYERS; i++) {
    ushort* nxt = bufs[i & 1];
    agg_bf<<<25000, 256, 0, stream>>>(cur, H0, ROW, EPK, nxt);
    float beta = logf(0.5f / (float)(i + 1) + 1.0f);
    conv_mfma<<<1563, 256, 0, stream>>>(nxt, WCONV + (size_t)i * HID_C * HID_C,
                                        1.0f - beta, beta);
    cur = nxt;
  }

  // decoder
  dec_mfma<<<3125, 256, 0, stream>>>(cur, WDEC, out);
}